// Round 19
// baseline (178.590 us; speedup 1.0000x reference)
//
#include <hip/hip_runtime.h>
#include <hip/hip_bf16.h>

// Pipeline: k_stats (IN mean/rstd) -> k_wprep (conv_w -> bf16 wT3 32x32-fragment layout)
//           k_mid (fused IN+dw3x3+pw+bias -> mid bf16 [b][h][w][c])
//           k_conv (implicit-GEMM 3x3 conv, MFMA 32x32x16; wave = 64o x 128pix
//                   = 2 o-tiles x 4 pix-tiles, acc 2x4xf32x16; c-major LDS
//                   [row][slot][w] -> dense conflict-free 32-wide B fragments;
//                   A prefetched one tap ahead, B one fragment ahead)

#define EPSV 1e-5f

typedef __attribute__((ext_vector_type(8))) short short8;
typedef __attribute__((ext_vector_type(4))) float f32x4;
typedef __attribute__((ext_vector_type(16))) float f32x16;

template<int N> struct IC { static constexpr int value = N; };

__device__ __forceinline__ unsigned short f2bf(float f) {
  union { float f; unsigned int u; } v; v.f = f;
  unsigned int r = v.u + 0x7FFFu + ((v.u >> 16) & 1u);   // RNE
  return (unsigned short)(r >> 16);
}

__device__ __forceinline__ int refl(int i, int n) {
  if (i < 0) i = -i;
  if (i >= n) i = 2 * n - 2 - i;
  return i;
}

// ---------------- kernel 1: instance-norm stats ----------------
__global__ __launch_bounds__(256) void k_stats(const float* __restrict__ x,
                                               float* __restrict__ mean,
                                               float* __restrict__ rstd) {
  int bc = blockIdx.x;
  const float4* xp = (const float4*)(x + (size_t)bc * 4096);
  int tid = threadIdx.x;
  float s = 0.f, q = 0.f;
#pragma unroll
  for (int k = 0; k < 4; ++k) {
    float4 v = xp[tid + k * 256];
    s += v.x + v.y + v.z + v.w;
    q += v.x * v.x + v.y * v.y + v.z * v.z + v.w * v.w;
  }
  __shared__ float s1[256], s2[256];
  s1[tid] = s; s2[tid] = q;
  __syncthreads();
  for (int st = 128; st > 0; st >>= 1) {
    if (tid < st) { s1[tid] += s1[tid + st]; s2[tid] += s2[tid + st]; }
    __syncthreads();
  }
  if (tid == 0) {
    float m = s1[0] * (1.f / 4096.f);
    float var = s2[0] * (1.f / 4096.f) - m * m;
    mean[bc] = m;
    rstd[bc] = rsqrtf(var + EPSV);
  }
}

// ---------------- kernel 2: conv_w[o][c][3][3] -> wT3 32x32-MFMA-fragment bf16
// flat = (((t*16 + ot)*32 + c16)*64 + l)*8 + e
//   o = ot*32 + (l&31), c = c16*16 + (l>>5)*8 + e
__global__ __launch_bounds__(256) void k_wprep(const float* __restrict__ cw,
                                               unsigned short* __restrict__ wT3) {
  int idx = blockIdx.x * 256 + threadIdx.x;  // 9*512*512
  int e = idx & 7;
  int l = (idx >> 3) & 63;
  int c16 = (idx >> 9) & 31;
  int ot = (idx >> 14) & 15;
  int t = idx >> 18;
  int o = ot * 32 + (l & 31);
  int c = c16 * 16 + (l >> 5) * 8 + e;
  wT3[idx] = f2bf(cw[((size_t)(o * 512 + c)) * 9 + t]);
}

// ---------------- kernel 3: fused IN + dw3x3 + pointwise + bias -> mid bf16 [b][h][w][c]
__global__ __launch_bounds__(256) void k_mid(const float* __restrict__ x,
                                             const float* __restrict__ wsp,
                                             const float* __restrict__ wpw,
                                             const float* __restrict__ bias,
                                             const float* __restrict__ mean,
                                             const float* __restrict__ rstd,
                                             unsigned short* __restrict__ mid) {
  int bid = blockIdx.x;                      // 8 * 16 * 4 = 512
  int cg = bid & 3;
  int hq = (bid >> 2) & 15;
  int b = bid >> 6;
  int h0 = hq * 4;
  int tid = threadIdx.x;
  int cl = tid & 31, wq = tid >> 5;
  __shared__ float xs[32 * 391];

  int rowm[6];
#pragma unroll
  for (int r = 0; r < 6; ++r) rowm[r] = refl(h0 - 1 + r, 64);

  for (int cc = 0; cc < 4; ++cc) {
    int cbase = cg * 128 + cc * 32;
    __syncthreads();
#pragma unroll
    for (int k = 0; k < 12; ++k) {
      int idx = tid + k * 256;
      int c = idx / 96, rem = idx % 96;
      int r = rem >> 4, w4 = rem & 15;
      float4 v = *(const float4*)(x + ((size_t)(b * 512 + cbase + c)) * 4096 +
                                  rowm[r] * 64 + w4 * 4);
      float* dst = &xs[c * 391 + r * 65 + w4 * 4];
      dst[0] = v.x; dst[1] = v.y; dst[2] = v.z; dst[3] = v.w;
    }
    __syncthreads();

    int gc = b * 512 + cbase + cl;
    float m = mean[gc], rs = rstd[gc];
    float wp = wpw[gc], bv = bias[gc];
    float wk[9], wsum = 0.f;
#pragma unroll
    for (int t = 0; t < 9; ++t) { wk[t] = wsp[(size_t)gc * 9 + t]; wsum += wk[t]; }

    const float* xr = &xs[cl * 391];
#pragma unroll
    for (int r = 0; r < 4; ++r) {
#pragma unroll
      for (int wi = 0; wi < 8; ++wi) {
        int w = wq * 8 + wi;
        int wm = refl(w - 1, 64), wp1 = refl(w + 1, 64);
        float acc = 0.f;
#pragma unroll
        for (int dy = 0; dy < 3; ++dy) {
          const float* row = xr + (r + dy) * 65;
          acc += wk[dy * 3 + 0] * row[wm] + wk[dy * 3 + 1] * row[w] +
                 wk[dy * 3 + 2] * row[wp1];
        }
        float y = (acc - m * wsum) * rs;
        mid[(((size_t)(b * 64 + h0 + r)) * 64 + w) * 512 + cbase + cl] =
            f2bf(y * wp + bv);
      }
    }
  }
}

// ---------------- kernel 4: final 3x3 conv, implicit GEMM, MFMA 32x32x16 ----------------
// grid 256 (1/CU); 8 waves; block = 256 o x (4 rows x 64 w).
// Wave = 64 o (2 tiles) x 128 pix (4 tiles): acc[2][4] f32x16. Per tap:
// 4 A-loads (L2, prefetched 1 tap ahead) + 8 B ds_reads (pipelined 1 ahead)
// + 16 MFMA. LDS c-major [row][slot][w]: 32-lane fragment = 512B dense.
__global__ __launch_bounds__(512, 2) void k_conv(const unsigned short* __restrict__ wT3,
                                                 const unsigned short* __restrict__ mid,
                                                 const float* __restrict__ cb,
                                                 float* __restrict__ out) {
  int nbid = (blockIdx.x & 7) * 32 + (blockIdx.x >> 3);  // XCD-chunked bijection
  int mt = nbid >> 7;                        // 0..1 (256 o each); const per XCD
  int b = (nbid >> 4) & 7;
  int h0 = (nbid & 15) * 4;
  int tid = threadIdx.x;
  int wid = tid >> 6, l = tid & 63;
  int wo = wid & 3, wn = wid >> 2;           // o-quad (64 o), pix-half (2 rows)
  int l31 = l & 31;
  int lso = (l >> 5) * 1024;                 // lane's c-octet slot byte offset

  __shared__ union {
    unsigned short bbuf[2][6 * 4 * 64 * 8];  // 2 x 24 KB: [row][slot][w][8c]
    float epi[64 * 132];                     // epilogue transpose (~33 KB)
  } sm;

  int hrow_[6];
#pragma unroll
  for (int r = 0; r < 6; ++r) hrow_[r] = refl(h0 - 1 + r, 64);

  // per-(wgrp,dx) reflected-w byte offsets (w'*16), wgrp = pt&1 half-row
  int wrv2[2][3];
#pragma unroll
  for (int i = 0; i < 2; ++i)
#pragma unroll
    for (int dx = 0; dx < 3; ++dx)
      wrv2[i][dx] = refl(i * 32 + l31 + dx - 1, 64) * 16;

  f32x16 acc[2][4];
#pragma unroll
  for (int i = 0; i < 2; ++i)
#pragma unroll
    for (int j = 0; j < 4; ++j)
#pragma unroll
      for (int r = 0; r < 16; ++r) acc[i][j][r] = 0.f;

  // B: one 32-c chunk -> LDS [row 6][slot 4][w 64][8c] = 24 KB, c-major, no swizzle
  auto stageB = [&](int pi, int cc) {
    char* dstbase = (char*)&sm.bbuf[pi][0];
#pragma unroll
    for (int i = 0; i < 3; ++i) {
      int ld = tid + i * 512;                // 0..1535
      int row = ld >> 8, rem = ld & 255, slot = rem >> 6, w = rem & 63;
      const unsigned short* src = mid +
          (((size_t)(b * 64 + hrow_[row])) * 64 + w) * 512 + cc * 32 + slot * 8;
      __builtin_amdgcn_global_load_lds(
          (const __attribute__((address_space(1))) void*)src,
          (__attribute__((address_space(3))) void*)(dstbase + ld * 16),
          16, 0, 0);
    }
  };

  stageB(0, 0);

  // per-wave A base: o-tiles otg = mt*8 + wo*2 + {0,1}
  const unsigned short* wa0 =
      wT3 + ((size_t)((mt * 8 + wo * 2) * 32)) * 512 + l * 8;
  // A-frag offset for (t, ot, cc, kh): t*262144 + ot*16384 + (cc*2+kh)*512

  // prologue: load A for first executed tap (rot = wn*4), chunk 0
  short8 aC[4];                              // [kh*2+ot]
  {
    const unsigned short* wp0 = wa0 + (size_t)(wn * 4) * 262144;
#pragma unroll
    for (int kh = 0; kh < 2; ++kh)
#pragma unroll
      for (int ot = 0; ot < 2; ++ot)
        aC[kh * 2 + ot] = *(const short8*)(wp0 + ot * 16384 + kh * 512);
  }

  for (int cc = 0; cc < 16; ++cc) {
    int pb = cc & 1;
    __syncthreads();                         // B(cc) landed; buf pb^1 free
    if (cc < 15) stageB(pb ^ 1, cc + 1);     // prefetch next chunk (9 taps of cover)
    const char* mb = (const char*)&sm.bbuf[pb][0];

    auto taps = [&](auto rotc) {
      constexpr int ROT = decltype(rotc)::value;
      const int dy0 = (ROT % 9) / 3, dx0 = (ROT % 9) % 3;
      // prime: first fragment (kh=0, pt=0)
      short8 bfC = *(const short8*)(mb + (wn * 2 + dy0) * 4096 + lso + wrv2[0][dx0]);
#pragma unroll
      for (int t = 0; t < 9; ++t) {
        const int tr = (t + ROT) % 9;        // compile-time rotated tap
        const int dy = tr / 3, dx = tr % 3;

        // prefetch NEXT tap's A (next chunk's first tap when t==8; wraps safely)
        const int trn = (t + 1 + ROT) % 9;
        const int dyn = trn / 3, dxn = trn % 3;
        const int ccn = (t < 8) ? cc : ((cc + 1) & 15);
        const unsigned short* wan = wa0 + (size_t)trn * 262144;
        short8 aN[4];
#pragma unroll
        for (int kh = 0; kh < 2; ++kh)
#pragma unroll
          for (int ot = 0; ot < 2; ++ot)
            aN[kh * 2 + ot] =
                *(const short8*)(wan + ot * 16384 + (size_t)(ccn * 2 + kh) * 512);

        __builtin_amdgcn_s_setprio(1);
#pragma unroll
        for (int kh = 0; kh < 2; ++kh)
#pragma unroll
          for (int pt = 0; pt < 4; ++pt) {
            // prefetch NEXT fragment's B while this fragment's MFMAs run
            const int f = kh * 4 + pt;
            short8 bfN;
            if (f < 7) {
              const int khn = (f + 1) >> 2, ptn = (f + 1) & 3;
              bfN = *(const short8*)(mb + (wn * 2 + (ptn >> 1) + dy) * 4096 +
                                     khn * 2048 + lso + wrv2[ptn & 1][dx]);
            } else if (t < 8) {
              bfN = *(const short8*)(mb + (wn * 2 + dyn) * 4096 +
                                     lso + wrv2[0][dxn]);
            } else {
              bfN = bfC;                     // chunk end: no cross-chunk prefetch
            }
#pragma unroll
            for (int ot = 0; ot < 2; ++ot)
              acc[ot][pt] = __builtin_amdgcn_mfma_f32_32x32x16_bf16(
                  aC[kh * 2 + ot], bfC, acc[ot][pt], 0, 0, 0);
            bfC = bfN;
          }
        __builtin_amdgcn_s_setprio(0);
#pragma unroll
        for (int i = 0; i < 4; ++i) aC[i] = aN[i];
      }
    };
    if (wn == 0) taps(IC<0>{});              // SIMD-mates (wid, wid+4) differ in wn
    else         taps(IC<4>{});              // -> de-phased by 4 taps
  }

  // ---- epilogue: LDS transpose -> coalesced float4 row stores (through L2) ----
  // 32x32 C/D layout: col(pixel) = l&31, row(o) = (reg&3) + 8*(reg>>2) + 4*(l>>5)
#pragma unroll
  for (int p = 0; p < 4; ++p)
#pragma unroll
    for (int s = 0; s < 2; ++s) {
      __syncthreads();
      if (wo == p && wn == s) {              // one wave: 64 o x 128 pix
#pragma unroll
        for (int ot = 0; ot < 2; ++ot)
#pragma unroll
          for (int pt = 0; pt < 4; ++pt) {
            int pix = (pt >> 1) * 64 + (pt & 1) * 32 + l31;   // 0..127
#pragma unroll
            for (int reg = 0; reg < 16; ++reg) {
              int ol = ot * 32 + (reg & 3) + 8 * (reg >> 2) + 4 * (l >> 5);
              sm.epi[ol * 132 + pix] = acc[ot][pt][reg];
            }
          }
      }
      __syncthreads();
#pragma unroll
      for (int it = 0; it < 4; ++it) {
        int idx = tid + it * 512;            // 0..2047 float4 units
        int ol = idx >> 5, rem = idx & 31;
        f32x4 v = *(const f32x4*)&sm.epi[ol * 132 + rem * 4];
        int o = mt * 256 + p * 64 + ol;
        float cbv = cb[o];
        v[0] += cbv; v[1] += cbv; v[2] += cbv; v[3] += cbv;
        int pix = rem * 4;
        int hh = h0 + s * 2 + (pix >> 6);
        int w4 = pix & 63;
        *(f32x4*)(out + (((size_t)(b * 512 + o)) * 64 + hh) * 64 + w4) = v;
      }
    }
}

extern "C" void kernel_launch(void* const* d_in, const int* in_sizes, int n_in,
                              void* d_out, int out_size, void* d_ws, size_t ws_size,
                              hipStream_t stream) {
  const float* x    = (const float*)d_in[0];
  const float* wsp  = (const float*)d_in[1];
  const float* wpw  = (const float*)d_in[2];
  const float* bias = (const float*)d_in[3];
  const float* cw   = (const float*)d_in[4];
  const float* cb   = (const float*)d_in[5];
  float* out = (float*)d_out;

  char* ws = (char*)d_ws;
  float* mean = (float*)ws;                              // 4096 f32
  float* rstd = (float*)(ws + 16384);                    // 4096 f32
  unsigned short* wT3 = (unsigned short*)(ws + 32768);   // 4.5 MB
  unsigned short* mid = (unsigned short*)(ws + 32768 + 9 * 512 * 512 * 2); // 32 MB

  k_stats<<<4096, 256, 0, stream>>>(x, mean, rstd);
  k_wprep<<<9216, 256, 0, stream>>>(cw, wT3);
  k_mid<<<512, 256, 0, stream>>>(x, wsp, wpw, bias, mean, rstd, mid);
  k_conv<<<256, 512, 0, stream>>>(wT3, mid, cb, out);
}

// Round 20
// 171.096 us; speedup vs baseline: 1.0438x; 1.0438x over previous
//
#include <hip/hip_runtime.h>
#include <hip/hip_bf16.h>

// Pipeline: k_stats (IN mean/rstd) -> k_wprep (conv_w -> bf16 wT2 fragment layout)
//           k_mid (fused IN+dw3x3+pw+bias -> mid bf16 [b][h][w][c])
//           k_conv (implicit-GEMM 3x3 conv, MFMA 16x16x32; wave = 64o x 128pix
//                   acc[4][8]; A prefetched one tap ahead (VMEM), B ds_reads
//                   software-pipelined one fragment ahead (LDS latency hides
//                   under the previous fragment's MFMA cluster))

#define EPSV 1e-5f

typedef __attribute__((ext_vector_type(8))) short short8;
typedef __attribute__((ext_vector_type(4))) float f32x4;

template<int N> struct IC { static constexpr int value = N; };

__device__ __forceinline__ unsigned short f2bf(float f) {
  union { float f; unsigned int u; } v; v.f = f;
  unsigned int r = v.u + 0x7FFFu + ((v.u >> 16) & 1u);   // RNE
  return (unsigned short)(r >> 16);
}

__device__ __forceinline__ int refl(int i, int n) {
  if (i < 0) i = -i;
  if (i >= n) i = 2 * n - 2 - i;
  return i;
}

// ---------------- kernel 1: instance-norm stats ----------------
__global__ __launch_bounds__(256) void k_stats(const float* __restrict__ x,
                                               float* __restrict__ mean,
                                               float* __restrict__ rstd) {
  int bc = blockIdx.x;
  const float4* xp = (const float4*)(x + (size_t)bc * 4096);
  int tid = threadIdx.x;
  float s = 0.f, q = 0.f;
#pragma unroll
  for (int k = 0; k < 4; ++k) {
    float4 v = xp[tid + k * 256];
    s += v.x + v.y + v.z + v.w;
    q += v.x * v.x + v.y * v.y + v.z * v.z + v.w * v.w;
  }
  __shared__ float s1[256], s2[256];
  s1[tid] = s; s2[tid] = q;
  __syncthreads();
  for (int st = 128; st > 0; st >>= 1) {
    if (tid < st) { s1[tid] += s1[tid + st]; s2[tid] += s2[tid + st]; }
    __syncthreads();
  }
  if (tid == 0) {
    float m = s1[0] * (1.f / 4096.f);
    float var = s2[0] * (1.f / 4096.f) - m * m;
    mean[bc] = m;
    rstd[bc] = rsqrtf(var + EPSV);
  }
}

// ---------------- kernel 2: conv_w[o][c][3][3] -> wT2 MFMA-fragment layout bf16
// flat = (((t*32 + o/16)*16 + c/32)*64 + (g*16 + o%16))*8 + e, g=(c%32)/8, e=c%8
__global__ __launch_bounds__(256) void k_wprep(const float* __restrict__ cw,
                                               unsigned short* __restrict__ wT2) {
  int idx = blockIdx.x * 256 + threadIdx.x;  // 9*512*512
  int e = idx & 7;
  int l15 = (idx >> 3) & 15;
  int g = (idx >> 7) & 3;
  int cq = (idx >> 9) & 15;
  int og = (idx >> 13) & 31;
  int t = idx >> 18;
  int o = og * 16 + l15;
  int c = cq * 32 + g * 8 + e;
  wT2[idx] = f2bf(cw[((size_t)(o * 512 + c)) * 9 + t]);
}

// ---------------- kernel 3: fused IN + dw3x3 + pointwise + bias -> mid bf16 [b][h][w][c]
__global__ __launch_bounds__(256) void k_mid(const float* __restrict__ x,
                                             const float* __restrict__ wsp,
                                             const float* __restrict__ wpw,
                                             const float* __restrict__ bias,
                                             const float* __restrict__ mean,
                                             const float* __restrict__ rstd,
                                             unsigned short* __restrict__ mid) {
  int bid = blockIdx.x;                      // 8 * 16 * 4 = 512
  int cg = bid & 3;
  int hq = (bid >> 2) & 15;
  int b = bid >> 6;
  int h0 = hq * 4;
  int tid = threadIdx.x;
  int cl = tid & 31, wq = tid >> 5;
  __shared__ float xs[32 * 391];

  int rowm[6];
#pragma unroll
  for (int r = 0; r < 6; ++r) rowm[r] = refl(h0 - 1 + r, 64);

  for (int cc = 0; cc < 4; ++cc) {
    int cbase = cg * 128 + cc * 32;
    __syncthreads();
#pragma unroll
    for (int k = 0; k < 12; ++k) {
      int idx = tid + k * 256;
      int c = idx / 96, rem = idx % 96;
      int r = rem >> 4, w4 = rem & 15;
      float4 v = *(const float4*)(x + ((size_t)(b * 512 + cbase + c)) * 4096 +
                                  rowm[r] * 64 + w4 * 4);
      float* dst = &xs[c * 391 + r * 65 + w4 * 4];
      dst[0] = v.x; dst[1] = v.y; dst[2] = v.z; dst[3] = v.w;
    }
    __syncthreads();

    int gc = b * 512 + cbase + cl;
    float m = mean[gc], rs = rstd[gc];
    float wp = wpw[gc], bv = bias[gc];
    float wk[9], wsum = 0.f;
#pragma unroll
    for (int t = 0; t < 9; ++t) { wk[t] = wsp[(size_t)gc * 9 + t]; wsum += wk[t]; }

    const float* xr = &xs[cl * 391];
#pragma unroll
    for (int r = 0; r < 4; ++r) {
#pragma unroll
      for (int wi = 0; wi < 8; ++wi) {
        int w = wq * 8 + wi;
        int wm = refl(w - 1, 64), wp1 = refl(w + 1, 64);
        float acc = 0.f;
#pragma unroll
        for (int dy = 0; dy < 3; ++dy) {
          const float* row = xr + (r + dy) * 65;
          acc += wk[dy * 3 + 0] * row[wm] + wk[dy * 3 + 1] * row[w] +
                 wk[dy * 3 + 2] * row[wp1];
        }
        float y = (acc - m * wsum) * rs;
        mid[(((size_t)(b * 64 + h0 + r)) * 64 + w) * 512 + cbase + cl] =
            f2bf(y * wp + bv);
      }
    }
  }
}

// ---------------- kernel 4: final 3x3 conv, implicit GEMM ----------------
// grid 256 (1/CU); 8 waves; block = 256 o x (4 rows x 64 w).
// Wave = 64 o x 128 pix (2 rows): acc[4][8]; A prefetched one tap ahead,
// B ds_reads pipelined one fragment ahead (bfC/bfN). Rotation kept.
__global__ __launch_bounds__(512, 2) void k_conv(const unsigned short* __restrict__ wT2,
                                                 const unsigned short* __restrict__ mid,
                                                 const float* __restrict__ cb,
                                                 float* __restrict__ out) {
  int nbid = (blockIdx.x & 7) * 32 + (blockIdx.x >> 3);  // XCD-chunked bijection
  int mt = nbid >> 7;                        // 0..1 (256 o each); const per XCD
  int b = (nbid >> 4) & 7;
  int h0 = (nbid & 15) * 4;
  int tid = threadIdx.x;
  int wid = tid >> 6, l = tid & 63;
  int wo = wid & 3, wn = wid >> 2;           // o-quad (64 o), pix-half (2 rows)
  int l15 = l & 15, g = l >> 4;

  __shared__ union {
    unsigned short bbuf[2][6 * 64 * 32];     // 2 x 24 KB (mid tile, 6 halo rows)
    float epi[64 * 132];                     // epilogue transpose (~33 KB)
  } sm;

  int hrow_[6];
#pragma unroll
  for (int r = 0; r < 6; ++r) hrow_[r] = refl(h0 - 1 + r, 64);

  // per-(ww,dx) B byte offsets (reflected w + bank-swizzle slot)
  int boff[4][3];
#pragma unroll
  for (int ww = 0; ww < 4; ++ww)
#pragma unroll
    for (int dx = 0; dx < 3; ++dx) {
      int wr = refl(ww * 16 + l15 + dx - 1, 64);
      int s = g ^ ((wr >> 1) & 3);
      boff[ww][dx] = wr * 64 + s * 16;
    }

  f32x4 acc[4][8];
  f32x4 zero = {0.f, 0.f, 0.f, 0.f};
#pragma unroll
  for (int i = 0; i < 4; ++i)
#pragma unroll
    for (int j = 0; j < 8; ++j) acc[i][j] = zero;

  // B: one 32-c chunk (6 rows x 64 w x 32 c = 24 KB), linear dest, swizzled src
  auto stageB = [&](int pi, int cc) {
    int cb32 = cc * 32;
    char* dstbase = (char*)&sm.bbuf[pi][0];
#pragma unroll
    for (int i = 0; i < 3; ++i) {
      int ld = tid + i * 512;                // 0..1535
      int row = ld >> 8, rem = ld & 255, w = rem >> 2, s = rem & 3;
      int gcg = s ^ ((w >> 1) & 3);
      const unsigned short* src = mid +
          (((size_t)(b * 64 + hrow_[row])) * 64 + w) * 512 + cb32 + gcg * 8;
      __builtin_amdgcn_global_load_lds(
          (const __attribute__((address_space(1))) void*)src,
          (__attribute__((address_space(3))) void*)(dstbase + ld * 16),
          16, 0, 0);
    }
  };

  stageB(0, 0);

  // per-wave A base: o-groups og = mt*16 + wo*4 + of (wave-private o-slice)
  const unsigned short* wa0 =
      wT2 + ((size_t)((mt * 16 + wo * 4) * 16)) * 512 + l * 8;

  // prologue: load A for the first executed tap (rot = wn*4), chunk 0
  short8 aC[4];
  {
    const unsigned short* wp0 = wa0 + (size_t)(wn * 4) * 262144;
#pragma unroll
    for (int of = 0; of < 4; ++of)
      aC[of] = *(const short8*)(wp0 + of * 8192);
  }

  for (int cc = 0; cc < 16; ++cc) {
    int pb = cc & 1;
    __syncthreads();                         // B(cc) landed; buf pb^1 free
    if (cc < 15) stageB(pb ^ 1, cc + 1);     // prefetch next chunk (9 taps of cover)
    const char* mb = (const char*)&sm.bbuf[pb][0];

    auto taps = [&](auto rotc) {
      constexpr int ROT = decltype(rotc)::value;
      const int dy0 = (ROT % 9) / 3, dx0 = (ROT % 9) % 3;
      short8 bfC = *(const short8*)(mb + (wn * 2 + dy0) * 4096 + boff[0][dx0]);
#pragma unroll
      for (int t = 0; t < 9; ++t) {
        const int tr = (t + ROT) % 9;        // compile-time rotated tap
        const int dy = tr / 3, dx = tr % 3;

        // prefetch NEXT tap's A (next chunk's first tap when t==8; wraps safely)
        const int trn = (t + 1 + ROT) % 9;
        const int dyn = trn / 3, dxn = trn % 3;
        const int ccn = (t < 8) ? cc : ((cc + 1) & 15);
        const unsigned short* wan =
            wa0 + (size_t)trn * 262144 + (size_t)ccn * 512;
        short8 aN[4];
#pragma unroll
        for (int of = 0; of < 4; ++of)
          aN[of] = *(const short8*)(wan + of * 8192);

        __builtin_amdgcn_s_setprio(1);
#pragma unroll
        for (int nf = 0; nf < 8; ++nf) {
          // prefetch NEXT fragment's B while this fragment's MFMAs run
          short8 bfN;
          if (nf < 7) {
            const int rowLn = wn * 2 + ((nf + 1) >> 2) + dy;
            bfN = *(const short8*)(mb + rowLn * 4096 + boff[(nf + 1) & 3][dx]);
          } else if (t < 8) {
            const int rowLn = wn * 2 + dyn;  // next tap's nf=0
            bfN = *(const short8*)(mb + rowLn * 4096 + boff[0][dxn]);
          } else {
            bfN = bfC;                       // chunk end: no cross-chunk prefetch
          }
#pragma unroll
          for (int of = 0; of < 4; ++of)
            acc[of][nf] = __builtin_amdgcn_mfma_f32_16x16x32_bf16(
                aC[of], bfC, acc[of][nf], 0, 0, 0);
          bfC = bfN;
        }
        __builtin_amdgcn_s_setprio(0);
#pragma unroll
        for (int of = 0; of < 4; ++of) aC[of] = aN[of];
      }
    };
    if (wn == 0) taps(IC<0>{});              // SIMD-mates (wid, wid+4) differ in wn
    else         taps(IC<4>{});              // -> de-phased by 4 taps
  }

  // ---- epilogue: LDS transpose -> coalesced float4 row stores (through L2) ----
#pragma unroll
  for (int p = 0; p < 4; ++p)
#pragma unroll
    for (int s = 0; s < 2; ++s) {
      __syncthreads();
      if (wo == p && wn == s) {              // one wave: 64 o x 128 pix
#pragma unroll
        for (int of = 0; of < 4; ++of)
#pragma unroll
          for (int nf = 0; nf < 8; ++nf) {
            int pix = (nf >> 2) * 64 + (nf & 3) * 16 + l15;  // 0..127
#pragma unroll
            for (int r = 0; r < 4; ++r) {
              int ol = of * 16 + g * 4 + r;  // 0..63
              sm.epi[ol * 132 + pix] = acc[of][nf][r];
            }
          }
      }
      __syncthreads();
#pragma unroll
      for (int it = 0; it < 4; ++it) {
        int idx = tid + it * 512;            // 0..2047 float4 units
        int ol = idx >> 5, rem = idx & 31;
        f32x4 v = *(const f32x4*)&sm.epi[ol * 132 + rem * 4];
        int o = mt * 256 + p * 64 + ol;
        float cbv = cb[o];
        v[0] += cbv; v[1] += cbv; v[2] += cbv; v[3] += cbv;
        int pix = rem * 4;
        int hh = h0 + s * 2 + (pix >> 6);
        int w4 = pix & 63;
        *(f32x4*)(out + (((size_t)(b * 512 + o)) * 64 + hh) * 64 + w4) = v;
      }
    }
}

extern "C" void kernel_launch(void* const* d_in, const int* in_sizes, int n_in,
                              void* d_out, int out_size, void* d_ws, size_t ws_size,
                              hipStream_t stream) {
  const float* x    = (const float*)d_in[0];
  const float* wsp  = (const float*)d_in[1];
  const float* wpw  = (const float*)d_in[2];
  const float* bias = (const float*)d_in[3];
  const float* cw   = (const float*)d_in[4];
  const float* cb   = (const float*)d_in[5];
  float* out = (float*)d_out;

  char* ws = (char*)d_ws;
  float* mean = (float*)ws;                              // 4096 f32
  float* rstd = (float*)(ws + 16384);                    // 4096 f32
  unsigned short* wT2 = (unsigned short*)(ws + 32768);   // 4.5 MB
  unsigned short* mid = (unsigned short*)(ws + 32768 + 9 * 512 * 512 * 2); // 32 MB

  k_stats<<<4096, 256, 0, stream>>>(x, mean, rstd);
  k_wprep<<<9216, 256, 0, stream>>>(cw, wT2);
  k_mid<<<512, 256, 0, stream>>>(x, wsp, wpw, bias, mean, rstd, mid);
  k_conv<<<256, 512, 0, stream>>>(wT2, mid, cb, out);
}